// Round 4
// baseline (40.816 us; speedup 1.0000x reference)
//
#include <hip/hip_runtime.h>
#include <math.h>

#define B 8
#define S 4096
#define H 1024
#define NSEG 64
#define NPARA 32
#define NA 8
#define BS (B * S)
#define PAD(i) ((i) + ((i) >> 4))
#define ROWS_PER_BLK 16
#define GROUPS 4                            // 4 groups x 4 rows per block
#define BLKS_PER_B (S / ROWS_PER_BLK)       // 256
#define NBLK (B * BLKS_PER_B)               // 2048

// async global->LDS, 16B per lane; lds dest must be wave-uniform base
__device__ __forceinline__ void gload_lds16(const float4* g, float4* l)
{
    __builtin_amdgcn_global_load_lds(
        (const __attribute__((address_space(1))) void*)g,
        (__attribute__((address_space(3))) void*)l, 16, 0, 0);
}

// online-LSE merge: x = running max, y = running scaled sum
__device__ __forceinline__ float2 lse_merge(float2 A, float2 Bv)
{
    float m = fmaxf(A.x, Bv.x);
    float s = 0.f;
    if (A.y > 0.f)  s += A.y * expf(A.x - m);
    if (Bv.y > 0.f) s += Bv.y * expf(Bv.x - m);
    return make_float2(m, s);
}

// ---------------------------------------------------------------------------
// Kernel 1: gload_lds-pipelined per-row 4-way dots + fused masked-LSE partials.
// Block = 16 rows of one batch, staged to LDS in 4 groups of 4 rows (16 KB),
// double-buffered: stage(g+1) in flight during compute(g), drained by the
// vmcnt(0) inside __syncthreads() (catalog T3 minimum 2-phase).
// Wave w computes row w of each group. Scores stored AoS float4 per row.
// ---------------------------------------------------------------------------
__global__ __launch_bounds__(256) void dots_kernel(
    const float4* __restrict__ seq4,
    const float*  __restrict__ Wqa,
    const float*  __restrict__ Wsp,
    const float*  __restrict__ Wrank,
    const int*    __restrict__ tt,
    float4* __restrict__ sc4,        // (B*S) AoS: {d_qa0, d_qa1, d_sp, d_rank}
    float4* __restrict__ lse_part,   // (NBLK) {m0,s0,m1,s1}
    float*  __restrict__ out)
{
    const int blk   = blockIdx.x;
    const int b     = blk >> 8;
    const int rbase = (blk & 255) * ROWS_PER_BLK;
    const int t     = threadIdx.x;
    const int w     = t >> 6, lane = t & 63;

    if (blk == 0 && t == 0) { out[0] = 0.f; out[1] = 0.f; out[2] = 0.f; }

    __shared__ float4 sbuf[2][1024];       // 2 x 16 KB staging
    __shared__ float4 lsep[4];

    // weight preload: lane covers float4 chunks (lane + 64c), c = 0..3
    float wq0[4][4], wq1[4][4];
    float4 wspv[4], wrkv[4];
#pragma unroll
    for (int c = 0; c < 4; ++c) {
        int h0 = (lane + 64 * c) * 4;
#pragma unroll
        for (int j = 0; j < 4; ++j) {
            wq0[c][j] = Wqa[(h0 + j) * 2 + 0];
            wq1[c][j] = Wqa[(h0 + j) * 2 + 1];
        }
        wspv[c] = *(const float4*)(Wsp + h0);
        wrkv[c] = *(const float4*)(Wrank + h0);
    }

    const size_t baseF4 = (size_t)(b * S + rbase) * (H / 4);
    const int    wbase  = t & ~63;          // w*64, wave-uniform

    // prologue: stage group 0
    {
        const float4* gsrc = seq4 + baseF4;
#pragma unroll
        for (int k = 0; k < 4; ++k)
            gload_lds16(gsrc + k * 256 + t, &sbuf[0][k * 256 + wbase]);
    }
    __syncthreads();                        // drains stage(0)

    const int* ttb = tt + b * S;
    float m0 = -INFINITY, s0 = 0.f, m1 = -INFINITY, s1 = 0.f;

    for (int g = 0; g < GROUPS; ++g) {
        if (g + 1 < GROUPS) {               // issue stage(g+1) before compute
            const float4* gsrc = seq4 + baseF4 + (size_t)(g + 1) * (4 * H / 4);
#pragma unroll
            for (int k = 0; k < 4; ++k)
                gload_lds16(gsrc + k * 256 + t, &sbuf[(g + 1) & 1][k * 256 + wbase]);
        }
        // compute row (rbase + g*4 + w) from sbuf[g&1]
        const float4* rowp = &sbuf[g & 1][w * 256];
        float a0 = 0.f, a1 = 0.f, a2 = 0.f, a3 = 0.f;
#pragma unroll
        for (int c = 0; c < 4; ++c) {
            float4 v = rowp[lane + 64 * c];
            a0 += v.x * wq0[c][0] + v.y * wq0[c][1] + v.z * wq0[c][2] + v.w * wq0[c][3];
            a1 += v.x * wq1[c][0] + v.y * wq1[c][1] + v.z * wq1[c][2] + v.w * wq1[c][3];
            a2 += v.x * wspv[c].x + v.y * wspv[c].y + v.z * wspv[c].z + v.w * wspv[c].w;
            a3 += v.x * wrkv[c].x + v.y * wrkv[c].y + v.z * wrkv[c].z + v.w * wrkv[c].w;
        }
#pragma unroll
        for (int off = 32; off > 0; off >>= 1) {
            a0 += __shfl_xor(a0, off);
            a1 += __shfl_xor(a1, off);
            a2 += __shfl_xor(a2, off);
            a3 += __shfl_xor(a3, off);
        }
        const int srow = rbase + g * 4 + w;
        if (ttb[srow] == 1) {               // fused online masked LSE (biases cancel)
            float mn = fmaxf(m0, a0);
            s0 = s0 * expf(m0 - mn) + expf(a0 - mn); m0 = mn;
            mn = fmaxf(m1, a1);
            s1 = s1 * expf(m1 - mn) + expf(a1 - mn); m1 = mn;
        }
        if (lane == 0)
            sc4[b * S + srow] = make_float4(a0, a1, a2, a3);
        __syncthreads();                    // drains stage(g+1) + LDS reuse sync
    }

    if (lane == 0) lsep[w] = make_float4(m0, s0, m1, s1);
    __syncthreads();
    if (t == 0) {
        float2 L0 = make_float2(lsep[0].x, lsep[0].y);
        float2 L1 = make_float2(lsep[0].z, lsep[0].w);
#pragma unroll
        for (int i = 1; i < 4; ++i) {
            L0 = lse_merge(L0, make_float2(lsep[i].x, lsep[i].y));
            L1 = lse_merge(L1, make_float2(lsep[i].z, lsep[i].w));
        }
        lse_part[blk] = make_float4(L0.x, L0.y, L1.x, L1.y);
    }
}

// ---------------------------------------------------------------------------
// block reduce (sum) for ListMLE
// ---------------------------------------------------------------------------
__device__ __forceinline__ float blk_reduce1(float v, float* wred1, int t)
{
    const int lane = t & 63, w = t >> 6;
#pragma unroll
    for (int off = 32; off > 0; off >>= 1) v += __shfl_xor(v, off);
    if (lane == 0) wred1[w] = v;
    __syncthreads();
    float r = wred1[0] + wred1[1] + wred1[2] + wred1[3];
    __syncthreads();
    return r;
}

__device__ float listmle_block(const float* fs, const float* fl, float* se,
                               int n, float* wred1, int t)
{
    if (t < n) se[t] = (fl[t] != -1.0f) ? expf(fs[t]) : 0.0f;
    __syncthreads();
    float lp = 0.0f;
    if (t < n && fl[t] >= 0.5f) {
        float fj = fl[t];
        float rest = 0.0f;
        for (int k = 0; k < n; ++k)
            if (fl[k] < fj) rest += se[k];
        lp = fs[t] - logf(se[t] + rest);
    }
    float tot = blk_reduce1(lp, wred1, t);
    return -tot;
}

// ---------------------------------------------------------------------------
// Kernel 2: one block per batch. Merge LSE partials, prefix-scan d_sp,
// 2x ListMLE, parallel span loss; atomicAdd into out.
// ---------------------------------------------------------------------------
__global__ __launch_bounds__(256) void batch_kernel(
    const float4* __restrict__ sc4,
    const float4* __restrict__ lse_part,
    const int*    __restrict__ tt,
    const int*    __restrict__ sent_starts,
    const int*    __restrict__ para_starts,
    const float*  __restrict__ para_labels,
    const float*  __restrict__ sp_labels,
    const int*    __restrict__ starts,
    const int*    __restrict__ ends,
    float* __restrict__ out)
{
    const int b = blockIdx.x;
    const int t = threadIdx.x;
    const int lane = t & 63, w = t >> 6;

    __shared__ float  a[PAD(S) + 1];
    __shared__ float4 lsew[4];
    __shared__ float  wred1[4];
    __shared__ float  fsb[1 + NSEG], flb[1 + NSEG], seb[1 + NSEG];
    __shared__ float  lse_sh[2];

    const float4* sb  = sc4 + (size_t)b * S;
    const int*    ttb = tt + b * S;

    // ---- merge 256 LSE partials ---------------------------------------------
    {
        float4 P = lse_part[b * BLKS_PER_B + t];
        float2 L0 = make_float2(P.x, P.y);
        float2 L1 = make_float2(P.z, P.w);
#pragma unroll
        for (int off = 32; off > 0; off >>= 1) {
            float2 O0 = make_float2(__shfl_xor(L0.x, off), __shfl_xor(L0.y, off));
            float2 O1 = make_float2(__shfl_xor(L1.x, off), __shfl_xor(L1.y, off));
            L0 = lse_merge(L0, O0);
            L1 = lse_merge(L1, O1);
        }
        if (lane == 0) lsew[w] = make_float4(L0.x, L0.y, L1.x, L1.y);
        __syncthreads();
        if (t == 0) {
            float2 M0 = make_float2(lsew[0].x, lsew[0].y);
            float2 M1 = make_float2(lsew[0].z, lsew[0].w);
#pragma unroll
            for (int i = 1; i < 4; ++i) {
                M0 = lse_merge(M0, make_float2(lsew[i].x, lsew[i].y));
                M1 = lse_merge(M1, make_float2(lsew[i].z, lsew[i].w));
            }
            lse_sh[0] = M0.x + logf(M0.y);
            lse_sh[1] = M1.x + logf(M1.y);
        }
    }

    // ---- exclusive prefix scan of d_sp over S -------------------------------
    {
        for (int s = t; s < S; s += 256) a[PAD(s)] = sb[s].z;
        __syncthreads();
        float vals[16];
        float run = 0.f;
        const int base = t * 16;
#pragma unroll
        for (int i = 0; i < 16; ++i) {
            run += a[PAD(base + i)];
            vals[i] = run;
        }
        float v = run;
#pragma unroll
        for (int off = 1; off < 64; off <<= 1) {
            float u = __shfl_up(v, off, 64);
            if (lane >= off) v += u;
        }
        if (lane == 63) wred1[w] = v;
        __syncthreads();
        float woff = 0.f;
        for (int i = 0; i < w; ++i) woff += wred1[i];
        const float excl = woff + v - run;
        __syncthreads();
#pragma unroll
        for (int i = 0; i < 16; ++i) a[PAD(base + i + 1)] = excl + vals[i];
        if (t == 0) a[PAD(0)] = 0.f;
        __syncthreads();
    }

    // ---- sp ListMLE ---------------------------------------------------------
    if (t == 0) { fsb[0] = sb[0].z; flb[0] = 0.5f; }       // sent_thres
    if (t < NSEG) {
        int st = sent_starts[b * (NSEG + 1) + t];
        int en = sent_starts[b * (NSEG + 1) + t + 1];
        int stc = min(max(st, 0), S);
        int enc = max(min(max(en, 0), S), stc + 1);
        float score;
        if (en != -1) {
            int encc = min(enc, S);
            score = (a[PAD(encc)] - a[PAD(stc)]) / (float)(enc - stc);
        } else {
            score = sb[S - 1].z;                           // d_sp at last row
        }
        fsb[1 + t] = score;
        flb[1 + t] = sp_labels[b * NSEG + t];
    }
    __syncthreads();
    float sp_loss_b = listmle_block(fsb, flb, seb, 1 + NSEG, wred1, t);

    // ---- rank ListMLE -------------------------------------------------------
    if (t == 0) { fsb[0] = sb[0].w; flb[0] = 0.5f; }       // rank_thres
    if (t < NPARA) {
        int ps = para_starts[b * NPARA + t];
        fsb[1 + t] = sb[ps].w;
        flb[1 + t] = para_labels[b * NPARA + t];
    }
    __syncthreads();
    float rank_loss_b = listmle_block(fsb, flb, seb, 1 + NPARA, wred1, t);

    // ---- span loss (parallel over answers) ----------------------------------
    float e_a = 0.f;
    if (t < NA) {
        const float lse0 = lse_sh[0], lse1 = lse_sh[1];
        int tsv = starts[b * NA + t];
        int tev = ends[b * NA + t];
        float lt = 0.f;
        if (tsv != -1) {
            int sf = min(max(tsv, 0), S - 1);
            float sl = (ttb[sf] == 1) ? sb[sf].x : -INFINITY;
            lt += -(sl - lse0);
        }
        if (tev != -1) {
            int sf = min(max(tev, 0), S - 1);
            float el = (ttb[sf] == 1) ? sb[sf].y : -INFINITY;
            lt += -(el - lse1);
        }
        float lp = -lt;
        e_a = (lp == 0.0f) ? 0.f : expf(lp);
    }
#pragma unroll
    for (int off = 4; off > 0; off >>= 1) e_a += __shfl_xor(e_a, off, 8);
    if (t == 0) {
        float logm = (e_a > 0.f) ? logf(e_a) : 0.f;
        atomicAdd(out + 0, rank_loss_b + sp_loss_b - logm);
        atomicAdd(out + 1, rank_loss_b);
        atomicAdd(out + 2, sp_loss_b);
    }
}

extern "C" void kernel_launch(void* const* d_in, const int* in_sizes, int n_in,
                              void* d_out, int out_size, void* d_ws, size_t ws_size,
                              hipStream_t stream)
{
    const float* seq         = (const float*)d_in[0];
    const int*   tt          = (const int*)  d_in[1];
    const int*   sent_starts = (const int*)  d_in[2];
    const int*   para_starts = (const int*)  d_in[3];
    const float* para_labels = (const float*)d_in[4];
    const float* sp_labels   = (const float*)d_in[5];
    const int*   starts      = (const int*)  d_in[6];
    const int*   ends        = (const int*)  d_in[7];
    const float* Wqa         = (const float*)d_in[8];
    const float* Wrank       = (const float*)d_in[10];
    const float* Wsp         = (const float*)d_in[12];

    float*  out      = (float*)d_out;
    float4* sc4      = (float4*)d_ws;           // B*S float4 = 512 KB
    float4* lse_part = sc4 + (size_t)BS;        // NBLK float4 = 32 KB

    dots_kernel<<<NBLK, 256, 0, stream>>>((const float4*)seq, Wqa, Wsp, Wrank,
                                          tt, sc4, lse_part, out);
    batch_kernel<<<B, 256, 0, stream>>>(sc4, lse_part, tt, sent_starts,
                                        para_starts, para_labels, sp_labels,
                                        starts, ends, out);
}